// Round 7
// baseline (283.081 us; speedup 1.0000x reference)
//
#include <hip/hip_runtime.h>
#include <hip/hip_bf16.h>

#define S_LEN 8192
#define NH 128
#define NM 16
#define NB 32
#define NBATCH 32

typedef __hip_bfloat16 bf16;
typedef unsigned short ushort_t;
typedef unsigned int uint_t;

typedef __bf16 bf16x8 __attribute__((ext_vector_type(8)));
typedef float floatx4 __attribute__((ext_vector_type(4)));

__device__ __forceinline__ float b2f(bf16 v){ return __bfloat162float(v); }
__device__ __forceinline__ float ldf(const void* p, long i, int f32){
    return f32 ? ((const float*)p)[i] : b2f(((const bf16*)p)[i]);
}
// A&S 7.1.26 erf, |eps|<=1.5e-7
__device__ __forceinline__ float gelu_fast(float x){
    float z = fabsf(x) * 0.70710678118654752440f;
    float t = __builtin_amdgcn_rcpf(__builtin_fmaf(0.3275911f, z, 1.0f));
    float p = t*(0.254829592f + t*(-0.284496736f + t*(1.421413741f +
              t*(-1.453152027f + t*1.061405429f))));
    float e = __expf(-z * z);
    float er = __builtin_fmaf(-p, e, 1.0f);
    float s = copysignf(er, x);
    return 0.5f * x * (1.0f + s);
}
__device__ __forceinline__ ushort_t f2us(float v){
    return __builtin_bit_cast(ushort_t, (__bf16)v);
}
__device__ __forceinline__ void split_bf(float v, ushort_t& hi, ushort_t& lo){
    __bf16 h = (__bf16)v;
    float r = v - (float)h;
    hi = __builtin_bit_cast(ushort_t, h);
    lo = __builtin_bit_cast(ushort_t, (__bf16)r);
}
__device__ __forceinline__ bf16x8 ld8(const ushort_t* p){
    return *(const bf16x8*)(const void*)p;
}
__device__ __forceinline__ floatx4 MF(bf16x8 a, bf16x8 b, floatx4 c){
    return __builtin_amdgcn_mfma_f32_16x16x32_bf16(a, b, c, 0, 0, 0);
}

// wave-0 dtype sniff (first 8 KB of x), broadcast via LDS. All threads call.
__device__ __forceinline__ int detect_f32(const void* x, int tid){
    __shared__ int sflag;
    if (tid < 64){
        const ushort_t* p = (const ushort_t*)x;
        int cnt = 0;
        for (int i = tid; i < 4096; i += 64){
            int e = (p[i] >> 7) & 0xFF;
            if (e >= 0xA0) cnt++;
        }
        #pragma unroll
        for (int off = 32; off > 0; off >>= 1) cnt += __shfl_xor(cnt, off, 64);
        if (tid == 0) sflag = (cnt > 400) ? 1 : 0;
    }
    __syncthreads();
    return sflag;
}

// full-width C prologue (k_final): fp32 C[b][j][k] -> scaled bf16 hi/lo B-frags.
__device__ __forceinline__ void c_prologue(const float* __restrict__ C,
                                           int b, int c, int q,
                                           bf16x8* Bhi, bf16x8* Blo){
    const float* Cb = C + (long)b * NB * NH;
    #pragma unroll
    for (int kt = 0; kt < 8; kt++){
        int k = kt * 16 + c;
        bf16x8 h8, l8;
        #pragma unroll
        for (int e = 0; e < 8; e++){
            int j = 8 * q + e;
            float sc = (j == 0) ? (1.0f / S_LEN)
                     : (j < NM) ? (2.0f / S_LEN)
                     : (j == NM) ? 0.f : (-2.0f / S_LEN);
            float v = Cb[j * NH + k] * sc;
            __bf16 hh = (__bf16)v;
            h8[e] = hh;
            l8[e] = (__bf16)(v - (float)hh);
        }
        Bhi[kt] = h8; Blo[kt] = l8;
    }
}

// ---- k_prep: blocks 0..511 modal DFT of x -> M; 512..1023 basis tables
__global__ __launch_bounds__(256) void k_prep(const void* __restrict__ x,
                                              const void* __restrict__ pw,
                                              const void* __restrict__ pb,
                                              float* __restrict__ M,
                                              ushort_t* __restrict__ Thi,
                                              ushort_t* __restrict__ Tlo,
                                              ushort_t* __restrict__ TThi){
    int bid = blockIdx.x;
    int tid = threadIdx.x;
    int f32 = detect_f32(x, tid);
    if (bid < 512){
        int m = bid >> 5, b = bid & 31;
        float re = 0.f, im = 0.f;
        #pragma unroll 4
        for (int s = tid; s < S_LEN; s += 256){
            float xv = ldf(x, (long)b * S_LEN + s, f32);
            if (m){
                int r = (m * s) & (S_LEN - 1);
                float rev = (float)r * (1.0f / (float)S_LEN);
                float sv = __builtin_amdgcn_sinf(rev);   // sin(2*pi*rev)
                float cv = __builtin_amdgcn_cosf(rev);
                re += xv * cv;
                im -= xv * sv;
            } else {
                re += xv;
            }
        }
        __shared__ float sred[8];
        #pragma unroll
        for (int off = 32; off > 0; off >>= 1){
            re += __shfl_xor(re, off, 64);
            im += __shfl_xor(im, off, 64);
        }
        int w = tid >> 6;
        if ((tid & 63) == 0){ sred[w] = re; sred[4 + w] = im; }
        __syncthreads();
        if (tid < NH){
            float Xre = sred[0] + sred[1] + sred[2] + sred[3];
            float Xim = sred[4] + sred[5] + sred[6] + sred[7];
            int h = tid;
            float pwv = ldf(pw, h, f32);
            float fc = pwv * Xre + (m == 0 ? (float)S_LEN * ldf(pb, h, f32) : 0.f);
            float fs = -pwv * Xim;
            float* Mb = M + (long)b * NB * NH;
            Mb[m * NH + h]        = fc;
            Mb[(NM + m) * NH + h] = fs;
        }
    } else {
        int bb = bid - 512;
        int s = bb * 16 + (tid >> 4);
        int m = tid & 15;
        float cv = 1.f, sv = 0.f;
        if (m){
            int r = (m * s) & (S_LEN - 1);
            float rev = (float)r * (1.0f / (float)S_LEN);
            sv = __builtin_amdgcn_sinf(rev);
            cv = __builtin_amdgcn_cosf(rev);
        }
        ushort_t chi, clo, shi, slo;
        split_bf(cv, chi, clo);
        split_bf(sv, shi, slo);
        Thi[s * NB + m] = chi;       Tlo[s * NB + m] = clo;
        Thi[s * NB + NM + m] = shi;  Tlo[s * NB + NM + m] = slo;
        TThi[m * S_LEN + s] = chi;
        TThi[(NM + m) * S_LEN + s] = shi;
    }
}

// ---- mixA (atomic-free): block (hc, mg, b) computes its h-chunk partial C
//      for 8 of 32 modes and plain-stores into private Cpart[hc] slice.
__global__ __launch_bounds__(256, 6) void k_mixA(const void* __restrict__ x,
                                                 const float* __restrict__ M,
                                                 const void* __restrict__ wre,
                                                 const void* __restrict__ wim,
                                                 long woff,
                                                 float* __restrict__ Cpart){
    int tid = threadIdx.x;
    int f32 = detect_f32(x, tid);
    int hc = blockIdx.x, mg = blockIdx.y, b = blockIdx.z;
    int k = tid & 127, msub = tid >> 7;
    int m0 = mg * 8 + msub * 4;     // 4 modes per thread
    int h0 = hc * 16;
    __shared__ float Ms[NB * 16];
    for (int i = tid; i < NB * 16; i += 256){
        int j = i >> 4, hh = i & 15;
        Ms[j * 16 + hh] = M[(long)b * NB * NH + j * NH + h0 + hh];
    }
    __syncthreads();
    float Cr[4] = {0,0,0,0}, Ci[4] = {0,0,0,0};
    #pragma unroll 4
    for (int hh = 0; hh < 16; hh++){
        long base = woff + ((long)(h0 + hh) * NH + k) * NM + m0;
        float wr[4], wi[4];
        if (f32){
            float4 a  = *(const float4*)((const float*)wre + base);
            float4 cc = *(const float4*)((const float*)wim + base);
            wr[0]=a.x;  wr[1]=a.y;  wr[2]=a.z;  wr[3]=a.w;
            wi[0]=cc.x; wi[1]=cc.y; wi[2]=cc.z; wi[3]=cc.w;
        } else {
            ushort4 a  = *(const ushort4*)((const ushort_t*)wre + base);
            ushort4 cc = *(const ushort4*)((const ushort_t*)wim + base);
            wr[0]=b2f(__builtin_bit_cast(bf16, a.x));
            wr[1]=b2f(__builtin_bit_cast(bf16, a.y));
            wr[2]=b2f(__builtin_bit_cast(bf16, a.z));
            wr[3]=b2f(__builtin_bit_cast(bf16, a.w));
            wi[0]=b2f(__builtin_bit_cast(bf16, cc.x));
            wi[1]=b2f(__builtin_bit_cast(bf16, cc.y));
            wi[2]=b2f(__builtin_bit_cast(bf16, cc.z));
            wi[3]=b2f(__builtin_bit_cast(bf16, cc.w));
        }
        #pragma unroll
        for (int e = 0; e < 4; e++){
            float fc = Ms[(m0 + e) * 16 + hh];
            float fs = Ms[(NM + m0 + e) * 16 + hh];
            Cr[e] += fc * wr[e] + fs * wi[e];
            Ci[e] += fc * wi[e] - fs * wr[e];
        }
    }
    float* Cb = Cpart + ((long)hc * NBATCH + b) * (NB * NH);
    #pragma unroll
    for (int e = 0; e < 4; e++){
        Cb[(m0 + e) * NH + k]        = Cr[e];
        Cb[(NM + m0 + e) * NH + k]   = Ci[e];
    }
}

// ---- k_redC: sum 8 hc-slices of Cpart -> C. Fully coalesced.
__global__ __launch_bounds__(256, 8) void k_redC(const float* __restrict__ Cpart,
                                                 float* __restrict__ C){
    int r = blockIdx.x, b = blockIdx.y;
    int i = r * 256 + threadIdx.x;          // 0..1023 over [j][k]
    const float* cp = Cpart + (long)b * (NB * NH) + i;
    float acc = 0.f;
    #pragma unroll
    for (int hc = 0; hc < 8; hc++) acc += cp[(long)hc * NBATCH * (NB * NH)];
    C[(long)b * (NB * NH) + i] = acc;
}

// ---- k_redM: sum the 64 per-block M partials -> Mfull. Fully coalesced.
__global__ __launch_bounds__(256, 8) void k_redM(const float* __restrict__ Mpart,
                                                 float* __restrict__ Mfull){
    int r = blockIdx.x, b = blockIdx.y;
    int idx = r * 256 + threadIdx.x;
    const float* mp = Mpart + (long)b * 64 * (NB * NH) + idx;
    float acc = 0.f;
    #pragma unroll 16
    for (int sx = 0; sx < 64; sx++) acc += mp[(long)sx * (NB * NH)];
    Mfull[(long)b * (NB * NH) + idx] = acc;
}

// ---- fused2: barrier-free fused layer, 128-s chunks (2048 blocks, 6/CU).
// Wave w owns k-chunk [32w,32w+32) over the block's 128 s.
__global__ __launch_bounds__(256, 6) void k_fused2(const ushort_t* __restrict__ Thi,
                                                   const ushort_t* __restrict__ Tlo,
                                                   const ushort_t* __restrict__ TThi,
                                                   const float* __restrict__ C,
                                                   float* __restrict__ Mpart){
    int b = blockIdx.y;
    int sx = blockIdx.x;                  // 0..63
    int tid = threadIdx.x;
    int w = tid >> 6;
    int lane = tid & 63;
    int c = lane & 15, q = lane >> 4;
    int kt0 = 2 * w;
    // per-wave scratch: 32 k-rows x 40 bf16 (pitch 40 => 80B, 16B-aligned rows)
    __shared__ __align__(16) ushort_t G[4][32][40];

    // C prologue restricted to this wave's two kt
    bf16x8 Bhi[2], Blo[2];
    {
        const float* Cb = C + (long)b * NB * NH;
        #pragma unroll
        for (int ktl = 0; ktl < 2; ktl++){
            int k = (kt0 + ktl) * 16 + c;
            bf16x8 h8, l8;
            #pragma unroll
            for (int e = 0; e < 8; e++){
                int j = 8 * q + e;
                float sc = (j == 0) ? (1.0f / S_LEN)
                         : (j < NM) ? (2.0f / S_LEN)
                         : (j == NM) ? 0.f : (-2.0f / S_LEN);
                float v = Cb[j * NH + k] * sc;
                __bf16 hh = (__bf16)v;
                h8[e] = hh;
                l8[e] = (__bf16)(v - (float)hh);
            }
            Bhi[ktl] = h8; Blo[ktl] = l8;
        }
    }

    floatx4 a00 = {0,0,0,0}, a01 = {0,0,0,0}, a10 = {0,0,0,0}, a11 = {0,0,0,0};
    int s0B = sx * 128;
    #pragma unroll 2
    for (int t2 = 0; t2 < 4; t2++){
        int sc0 = s0B + 32 * t2;
        bf16x8 Ahi[2], Alo[2];
        #pragma unroll
        for (int tt = 0; tt < 2; tt++){
            long ar = (long)(sc0 + 16 * tt + c) * NB + 8 * q;
            Ahi[tt] = ld8(Thi + ar);
            Alo[tt] = ld8(Tlo + ar);
        }
        bf16x8 Att0 = ld8(TThi + (long)c * S_LEN + sc0 + 8 * q);
        bf16x8 Att1 = ld8(TThi + (long)(16 + c) * S_LEN + sc0 + 8 * q);
        // synth -> gelu -> pack -> wave-private LDS write [k-local][s-local]
        #pragma unroll
        for (int tt = 0; tt < 2; tt++){
            #pragma unroll
            for (int ktl = 0; ktl < 2; ktl++){
                floatx4 acc = {0.f, 0.f, 0.f, 0.f};
                acc = MF(Ahi[tt], Bhi[ktl], acc);
                acc = MF(Alo[tt], Bhi[ktl], acc);
                acc = MF(Ahi[tt], Blo[ktl], acc);
                uint_t u0 = (uint_t)f2us(gelu_fast(acc[0])) |
                            ((uint_t)f2us(gelu_fast(acc[1])) << 16);
                uint_t u1 = (uint_t)f2us(gelu_fast(acc[2])) |
                            ((uint_t)f2us(gelu_fast(acc[3])) << 16);
                uint2 uu; uu.x = u0; uu.y = u1;
                *(uint2*)(void*)&G[w][16 * ktl + c][16 * tt + 4 * q] = uu;
            }
        }
        // transpose read: lane (c,q) gets h[s-local=8q+e][k-local=16*ktl+c]
        bf16x8 P0 = *(const bf16x8*)(const void*)&G[w][c][8 * q];
        bf16x8 P1 = *(const bf16x8*)(const void*)&G[w][16 + c][8 * q];
        a00 = MF(Att0, P0, a00);
        a01 = MF(Att0, P1, a01);
        a10 = MF(Att1, P0, a10);
        a11 = MF(Att1, P1, a11);
    }
    // block-private partial M slice: plain coalesced stores
    float* Mb = Mpart + ((long)b * 64 + sx) * (NB * NH);
    #pragma unroll
    for (int r = 0; r < 4; r++){
        Mb[(4 * q + r) * NH + kt0 * 16 + c]            = a00[r];
        Mb[(4 * q + r) * NH + (kt0 + 1) * 16 + c]      = a01[r];
        Mb[(16 + 4 * q + r) * NH + kt0 * 16 + c]       = a10[r];
        Mb[(16 + 4 * q + r) * NH + (kt0 + 1) * 16 + c] = a11[r];
    }
}

// ---- final: C prologue -> MFMA synth (ILP-grouped) -> out
__global__ __launch_bounds__(256, 4) void k_final(const void* __restrict__ x,
                                                  const ushort_t* __restrict__ Thi,
                                                  const ushort_t* __restrict__ Tlo,
                                                  const float* __restrict__ C,
                                                  const void* __restrict__ ow,
                                                  const void* __restrict__ ob,
                                                  void* __restrict__ out){
    int tid = threadIdx.x;
    int f32 = detect_f32(x, tid);
    int b = blockIdx.y;
    int s0 = blockIdx.x * 128;
    int w = tid >> 6;
    int lane = tid & 63;
    int c = lane & 15, q = lane >> 4;

    bf16x8 Bhi[8], Blo[8];
    c_prologue(C, b, c, q, Bhi, Blo);
    float ow8[8];
    #pragma unroll
    for (int kt = 0; kt < 8; kt++) ow8[kt] = ldf(ow, kt * 16 + c, f32);
    float obv = ldf(ob, 0, f32);
    #pragma unroll
    for (int sti = 0; sti < 2; sti++){
        int st = w * 2 + sti;
        long ar = (long)(s0 + st * 16 + c) * NB + 8 * q;
        bf16x8 Ahi = ld8(Thi + ar);
        bf16x8 Alo = ld8(Tlo + ar);
        float p0 = 0.f, p1 = 0.f, p2 = 0.f, p3 = 0.f;
        #pragma unroll
        for (int g = 0; g < 2; g++){
            int k0 = g * 4;
            floatx4 ac[4];
            #pragma unroll
            for (int t = 0; t < 4; t++) ac[t] = (floatx4){0.f, 0.f, 0.f, 0.f};
            #pragma unroll
            for (int t = 0; t < 4; t++) ac[t] = MF(Ahi, Bhi[k0 + t], ac[t]);
            #pragma unroll
            for (int t = 0; t < 4; t++) ac[t] = MF(Alo, Bhi[k0 + t], ac[t]);
            #pragma unroll
            for (int t = 0; t < 4; t++) ac[t] = MF(Ahi, Blo[k0 + t], ac[t]);
            #pragma unroll
            for (int t = 0; t < 4; t++){
                float o = ow8[k0 + t];
                p0 += gelu_fast(ac[t][0]) * o;
                p1 += gelu_fast(ac[t][1]) * o;
                p2 += gelu_fast(ac[t][2]) * o;
                p3 += gelu_fast(ac[t][3]) * o;
            }
        }
        #pragma unroll
        for (int off = 1; off < 16; off <<= 1){
            p0 += __shfl_xor(p0, off, 16);
            p1 += __shfl_xor(p1, off, 16);
            p2 += __shfl_xor(p2, off, 16);
            p3 += __shfl_xor(p3, off, 16);
        }
        if (c == 0){
            long s = s0 + st * 16 + 4 * q;
            if (f32){
                float4 v = {p0 + obv, p1 + obv, p2 + obv, p3 + obv};
                *(float4*)((float*)out + (long)b * S_LEN + s) = v;
            } else {
                uint_t u0 = (uint_t)f2us(p0 + obv) | ((uint_t)f2us(p1 + obv) << 16);
                uint_t u1 = (uint_t)f2us(p2 + obv) | ((uint_t)f2us(p3 + obv) << 16);
                uint_t* gp = (uint_t*)((ushort_t*)out + (long)b * S_LEN + s);
                gp[0] = u0; gp[1] = u1;
            }
        }
    }
}

extern "C" void kernel_launch(void* const* d_in, const int* in_sizes, int n_in,
                              void* d_out, int out_size, void* d_ws, size_t ws_size,
                              hipStream_t stream) {
    const void* x   = d_in[0];
    const void* pw  = d_in[1];
    const void* pb  = d_in[2];
    const void* wre = d_in[3];
    const void* wim = d_in[4];
    const void* ow  = d_in[5];
    const void* ob  = d_in[6];

    char* ws = (char*)d_ws;
    ushort_t* Thi  = (ushort_t*)(ws);                  // 512 KB
    ushort_t* Tlo  = (ushort_t*)(ws + (512u << 10));   // 512 KB
    ushort_t* TThi = (ushort_t*)(ws + (1024u << 10));  // 512 KB
    float* C     = (float*)(ws + (1536u << 10));       // 512 KB fp32 C
    float* Mfull = (float*)(ws + (2048u << 10));       // 512 KB fp32 M
    float* Cpart = (float*)(ws + (2560u << 10));       // 4 MB fp32 [hc][b][j][k]
    float* Mpart = (float*)(ws + (6656u << 10));       // 32 MB fp32 [b][sx][j][k]

    const long wstride = (long)NH * NH * NM;

    k_prep<<<1024, 256, 0, stream>>>(x, pw, pb, Mfull, Thi, Tlo, TThi);
    for (int l = 0; l < 4; l++){
        k_mixA<<<dim3(8, 2, NBATCH), 256, 0, stream>>>(x, Mfull, wre, wim,
                                                       l * wstride, Cpart);
        k_redC<<<dim3(4, NBATCH), 256, 0, stream>>>(Cpart, C);
        if (l < 3){
            k_fused2<<<dim3(64, NBATCH), 256, 0, stream>>>(Thi, Tlo, TThi,
                                                           C, Mpart);
            k_redM<<<dim3(16, NBATCH), 256, 0, stream>>>(Mpart, Mfull);
        } else {
            k_final<<<dim3(64, NBATCH), 256, 0, stream>>>(x, Thi, Tlo, C,
                                                          ow, ob, d_out);
        }
    }
}

// Round 8
// 271.580 us; speedup vs baseline: 1.0423x; 1.0423x over previous
//
#include <hip/hip_runtime.h>
#include <hip/hip_bf16.h>

#define S_LEN 8192
#define NH 128
#define NM 16
#define NB 32
#define NBATCH 32

typedef __hip_bfloat16 bf16;
typedef unsigned short ushort_t;
typedef unsigned int uint_t;

typedef __bf16 bf16x8 __attribute__((ext_vector_type(8)));
typedef float floatx4 __attribute__((ext_vector_type(4)));

__device__ __forceinline__ float b2f(bf16 v){ return __bfloat162float(v); }
__device__ __forceinline__ float ldf(const void* p, long i, int f32){
    return f32 ? ((const float*)p)[i] : b2f(((const bf16*)p)[i]);
}
// A&S 7.1.26 erf, |eps|<=1.5e-7
__device__ __forceinline__ float gelu_fast(float x){
    float z = fabsf(x) * 0.70710678118654752440f;
    float t = __builtin_amdgcn_rcpf(__builtin_fmaf(0.3275911f, z, 1.0f));
    float p = t*(0.254829592f + t*(-0.284496736f + t*(1.421413741f +
              t*(-1.453152027f + t*1.061405429f))));
    float e = __expf(-z * z);
    float er = __builtin_fmaf(-p, e, 1.0f);
    float s = copysignf(er, x);
    return 0.5f * x * (1.0f + s);
}
__device__ __forceinline__ ushort_t f2us(float v){
    return __builtin_bit_cast(ushort_t, (__bf16)v);
}
__device__ __forceinline__ void split_bf(float v, ushort_t& hi, ushort_t& lo){
    __bf16 h = (__bf16)v;
    float r = v - (float)h;
    hi = __builtin_bit_cast(ushort_t, h);
    lo = __builtin_bit_cast(ushort_t, (__bf16)r);
}
__device__ __forceinline__ bf16x8 ld8(const ushort_t* p){
    return *(const bf16x8*)(const void*)p;
}
__device__ __forceinline__ floatx4 MF(bf16x8 a, bf16x8 b, floatx4 c){
    return __builtin_amdgcn_mfma_f32_16x16x32_bf16(a, b, c, 0, 0, 0);
}

// wave-0 dtype sniff (first 8 KB of x), broadcast via LDS. All threads call.
__device__ __forceinline__ int detect_f32(const void* x, int tid){
    __shared__ int sflag;
    if (tid < 64){
        const ushort_t* p = (const ushort_t*)x;
        int cnt = 0;
        for (int i = tid; i < 4096; i += 64){
            int e = (p[i] >> 7) & 0xFF;
            if (e >= 0xA0) cnt++;
        }
        #pragma unroll
        for (int off = 32; off > 0; off >>= 1) cnt += __shfl_xor(cnt, off, 64);
        if (tid == 0) sflag = (cnt > 400) ? 1 : 0;
    }
    __syncthreads();
    return sflag;
}

// full-width C prologue (k_final): fp32 C[b][j][k] -> scaled bf16 hi/lo B-frags.
__device__ __forceinline__ void c_prologue(const float* __restrict__ C,
                                           int b, int c, int q,
                                           bf16x8* Bhi, bf16x8* Blo){
    const float* Cb = C + (long)b * NB * NH;
    #pragma unroll
    for (int kt = 0; kt < 8; kt++){
        int k = kt * 16 + c;
        bf16x8 h8, l8;
        #pragma unroll
        for (int e = 0; e < 8; e++){
            int j = 8 * q + e;
            float sc = (j == 0) ? (1.0f / S_LEN)
                     : (j < NM) ? (2.0f / S_LEN)
                     : (j == NM) ? 0.f : (-2.0f / S_LEN);
            float v = Cb[j * NH + k] * sc;
            __bf16 hh = (__bf16)v;
            h8[e] = hh;
            l8[e] = (__bf16)(v - (float)hh);
        }
        Bhi[kt] = h8; Blo[kt] = l8;
    }
}

// ---- k_prep: blocks 0..511 modal DFT of x -> M; 512..1023 basis tables + zero C0
__global__ __launch_bounds__(256) void k_prep(const void* __restrict__ x,
                                              const void* __restrict__ pw,
                                              const void* __restrict__ pb,
                                              float* __restrict__ M,
                                              ushort_t* __restrict__ Thi,
                                              ushort_t* __restrict__ Tlo,
                                              ushort_t* __restrict__ TThi,
                                              float* __restrict__ C0){
    int bid = blockIdx.x;
    int tid = threadIdx.x;
    int f32 = detect_f32(x, tid);
    if (bid < 512){
        int m = bid >> 5, b = bid & 31;
        float re = 0.f, im = 0.f;
        #pragma unroll 4
        for (int s = tid; s < S_LEN; s += 256){
            float xv = ldf(x, (long)b * S_LEN + s, f32);
            if (m){
                int r = (m * s) & (S_LEN - 1);
                float rev = (float)r * (1.0f / (float)S_LEN);
                float sv = __builtin_amdgcn_sinf(rev);   // sin(2*pi*rev)
                float cv = __builtin_amdgcn_cosf(rev);
                re += xv * cv;
                im -= xv * sv;
            } else {
                re += xv;
            }
        }
        __shared__ float sred[8];
        #pragma unroll
        for (int off = 32; off > 0; off >>= 1){
            re += __shfl_xor(re, off, 64);
            im += __shfl_xor(im, off, 64);
        }
        int w = tid >> 6;
        if ((tid & 63) == 0){ sred[w] = re; sred[4 + w] = im; }
        __syncthreads();
        if (tid < NH){
            float Xre = sred[0] + sred[1] + sred[2] + sred[3];
            float Xim = sred[4] + sred[5] + sred[6] + sred[7];
            int h = tid;
            float pwv = ldf(pw, h, f32);
            float fc = pwv * Xre + (m == 0 ? (float)S_LEN * ldf(pb, h, f32) : 0.f);
            float fs = -pwv * Xim;
            float* Mb = M + (long)b * NB * NH;
            Mb[m * NH + h]        = fc;
            Mb[(NM + m) * NH + h] = fs;
        }
    } else {
        int bb = bid - 512;
        int s = bb * 16 + (tid >> 4);
        int m = tid & 15;
        float cv = 1.f, sv = 0.f;
        if (m){
            int r = (m * s) & (S_LEN - 1);
            float rev = (float)r * (1.0f / (float)S_LEN);
            sv = __builtin_amdgcn_sinf(rev);
            cv = __builtin_amdgcn_cosf(rev);
        }
        ushort_t chi, clo, shi, slo;
        split_bf(cv, chi, clo);
        split_bf(sv, shi, slo);
        Thi[s * NB + m] = chi;       Tlo[s * NB + m] = clo;
        Thi[s * NB + NM + m] = shi;  Tlo[s * NB + NM + m] = slo;
        TThi[m * S_LEN + s] = chi;
        TThi[(NM + m) * S_LEN + s] = shi;
        C0[bb * 256 + tid] = 0.f;    // zero layer-0 C buffer
    }
}

// ---- mixA (round-6 form): stage M[b] 16-h chunk -> partial C -> atomic C.
__global__ __launch_bounds__(256) void k_mixA(const void* __restrict__ x,
                                              const float* __restrict__ M,
                                              const void* __restrict__ wre,
                                              const void* __restrict__ wim,
                                              long woff,
                                              float* __restrict__ C){
    int tid = threadIdx.x;
    int f32 = detect_f32(x, tid);
    int hc = blockIdx.x, b = blockIdx.y;
    int k = tid & 127, mh = tid >> 7;
    int m0 = mh * 8;
    int h0 = hc * 16;
    __shared__ float Ms[NB * 16];
    for (int i = tid; i < NB * 16; i += 256){
        int j = i >> 4, hh = i & 15;
        Ms[j * 16 + hh] = M[(long)b * NB * NH + j * NH + h0 + hh];
    }
    __syncthreads();
    float Cr[8] = {0,0,0,0,0,0,0,0}, Ci[8] = {0,0,0,0,0,0,0,0};
    #pragma unroll 4
    for (int hh = 0; hh < 16; hh++){
        long base = woff + ((long)(h0 + hh) * NH + k) * NM + m0;
        float wr[8], wi[8];
        if (f32){
            const float4* wr4 = (const float4*)((const float*)wre + base);
            const float4* wi4 = (const float4*)((const float*)wim + base);
            float4 a0 = wr4[0], a1 = wr4[1], c0 = wi4[0], c1 = wi4[1];
            wr[0]=a0.x; wr[1]=a0.y; wr[2]=a0.z; wr[3]=a0.w;
            wr[4]=a1.x; wr[5]=a1.y; wr[6]=a1.z; wr[7]=a1.w;
            wi[0]=c0.x; wi[1]=c0.y; wi[2]=c0.z; wi[3]=c0.w;
            wi[4]=c1.x; wi[5]=c1.y; wi[6]=c1.z; wi[7]=c1.w;
        } else {
            bf16x8 a = ld8((const ushort_t*)wre + base);
            bf16x8 c = ld8((const ushort_t*)wim + base);
            #pragma unroll
            for (int e = 0; e < 8; e++){ wr[e] = (float)a[e]; wi[e] = (float)c[e]; }
        }
        #pragma unroll
        for (int e = 0; e < 8; e++){
            float fc = Ms[(m0 + e) * 16 + hh];
            float fs = Ms[(NM + m0 + e) * 16 + hh];
            Cr[e] += fc * wr[e] + fs * wi[e];
            Ci[e] += fc * wi[e] - fs * wr[e];
        }
    }
    float* Cb = C + (long)b * NB * NH;
    #pragma unroll
    for (int e = 0; e < 8; e++){
        atomicAdd(&Cb[(m0 + e) * NH + k],      Cr[e]);
        atomicAdd(&Cb[(NM + m0 + e) * NH + k], Ci[e]);
    }
}

// ---- k_reduce: sum the 32 per-block M partials -> Mfull. Fully coalesced.
__global__ __launch_bounds__(256) void k_reduce(const float* __restrict__ Mpart,
                                                float* __restrict__ Mfull){
    int r = blockIdx.x, b = blockIdx.y;
    int idx = r * 256 + threadIdx.x;
    const float* mp = Mpart + (long)b * 32 * (NB * NH) + idx;
    float acc = 0.f;
    #pragma unroll
    for (int sx = 0; sx < 32; sx++) acc += mp[(long)sx * (NB * NH)];
    Mfull[(long)b * (NB * NH) + idx] = acc;
}

// ---- fused3: full-occupancy fused layer. 512 thr / 8 waves per block;
// wave w owns k-chunk [16w,16w+16) over the block's 256 s. 32 waves/CU
// (launch_bounds(512,8) caps VGPR at 64). Barrier-free; wave-private LDS
// transpose scratch G[w][16 k][40] (pitch-padded).
__global__ __launch_bounds__(512, 8) void k_fused3(const ushort_t* __restrict__ Thi,
                                                   const ushort_t* __restrict__ Tlo,
                                                   const ushort_t* __restrict__ TThi,
                                                   const float* __restrict__ C,
                                                   float* __restrict__ Cnext,
                                                   float* __restrict__ Mpart){
    int b = blockIdx.y;
    int sx = blockIdx.x;                  // 0..31, 256-s chunk
    int tid = threadIdx.x;
    int w = tid >> 6;                     // 0..7
    int lane = tid & 63;
    int c = lane & 15, q = lane >> 4;
    __shared__ __align__(16) ushort_t G[8][16][40];   // 10.2 KB

    // C prologue restricted to this wave's single kt = w
    bf16x8 Bhi, Blo;
    {
        const float* Cb = C + (long)b * NB * NH;
        int k = 16 * w + c;
        #pragma unroll
        for (int e = 0; e < 8; e++){
            int j = 8 * q + e;
            float sc = (j == 0) ? (1.0f / S_LEN)
                     : (j < NM) ? (2.0f / S_LEN)
                     : (j == NM) ? 0.f : (-2.0f / S_LEN);
            float v = Cb[j * NH + k] * sc;
            __bf16 hh = (__bf16)v;
            Bhi[e] = hh;
            Blo[e] = (__bf16)(v - (float)hh);
        }
    }
    // zero next-layer C slice (consumed by next mixA's atomics)
    if (tid < 32){
        *(float4*)(Cnext + (long)b * NB * NH + sx * 128 + tid * 4)
            = (float4){0.f, 0.f, 0.f, 0.f};
    }

    floatx4 a00 = {0,0,0,0}, a10 = {0,0,0,0};
    int s0B = sx * 256;
    for (int t2 = 0; t2 < 8; t2++){
        int sc0 = s0B + 32 * t2;
        bf16x8 Att0 = ld8(TThi + (long)c * S_LEN + sc0 + 8 * q);
        bf16x8 Att1 = ld8(TThi + (long)(16 + c) * S_LEN + sc0 + 8 * q);
        // synth -> gelu -> pack -> wave-private LDS write G[k-local][s-local]
        #pragma unroll
        for (int sti = 0; sti < 2; sti++){
            long ar = (long)(sc0 + 16 * sti + c) * NB + 8 * q;
            bf16x8 Ahi = ld8(Thi + ar);
            bf16x8 Alo = ld8(Tlo + ar);
            floatx4 acc = {0.f, 0.f, 0.f, 0.f};
            acc = MF(Ahi, Bhi, acc);
            acc = MF(Alo, Bhi, acc);
            acc = MF(Ahi, Blo, acc);
            uint_t u0 = (uint_t)f2us(gelu_fast(acc[0])) |
                        ((uint_t)f2us(gelu_fast(acc[1])) << 16);
            uint_t u1 = (uint_t)f2us(gelu_fast(acc[2])) |
                        ((uint_t)f2us(gelu_fast(acc[3])) << 16);
            uint2 uu; uu.x = u0; uu.y = u1;
            // row = c (k-local), col = s-local 16*sti + 4q .. +3
            *(uint2*)(void*)&G[w][c][16 * sti + 4 * q] = uu;
        }
        // transpose read: lane (c,q) gets B[s-local=8q+e][k-local=c]
        bf16x8 P0 = *(const bf16x8*)(const void*)&G[w][c][8 * q];
        a00 = MF(Att0, P0, a00);
        a10 = MF(Att1, P0, a10);
    }
    // block-private partial M slice: plain coalesced stores
    float* Mb = Mpart + ((long)b * 32 + sx) * (NB * NH);
    #pragma unroll
    for (int r = 0; r < 4; r++){
        Mb[(4 * q + r) * NH + 16 * w + c]        = a00[r];
        Mb[(16 + 4 * q + r) * NH + 16 * w + c]   = a10[r];
    }
}

// ---- final: C prologue -> MFMA synth (ILP-grouped) -> out
__global__ __launch_bounds__(256, 4) void k_final(const void* __restrict__ x,
                                                  const ushort_t* __restrict__ Thi,
                                                  const ushort_t* __restrict__ Tlo,
                                                  const float* __restrict__ C,
                                                  const void* __restrict__ ow,
                                                  const void* __restrict__ ob,
                                                  void* __restrict__ out){
    int tid = threadIdx.x;
    int f32 = detect_f32(x, tid);
    int b = blockIdx.y;
    int s0 = blockIdx.x * 128;
    int w = tid >> 6;
    int lane = tid & 63;
    int c = lane & 15, q = lane >> 4;

    bf16x8 Bhi[8], Blo[8];
    c_prologue(C, b, c, q, Bhi, Blo);
    float ow8[8];
    #pragma unroll
    for (int kt = 0; kt < 8; kt++) ow8[kt] = ldf(ow, kt * 16 + c, f32);
    float obv = ldf(ob, 0, f32);
    #pragma unroll
    for (int sti = 0; sti < 2; sti++){
        int st = w * 2 + sti;
        long ar = (long)(s0 + st * 16 + c) * NB + 8 * q;
        bf16x8 Ahi = ld8(Thi + ar);
        bf16x8 Alo = ld8(Tlo + ar);
        float p0 = 0.f, p1 = 0.f, p2 = 0.f, p3 = 0.f;
        #pragma unroll
        for (int g = 0; g < 2; g++){
            int k0 = g * 4;
            floatx4 ac[4];
            #pragma unroll
            for (int t = 0; t < 4; t++) ac[t] = (floatx4){0.f, 0.f, 0.f, 0.f};
            #pragma unroll
            for (int t = 0; t < 4; t++) ac[t] = MF(Ahi, Bhi[k0 + t], ac[t]);
            #pragma unroll
            for (int t = 0; t < 4; t++) ac[t] = MF(Alo, Bhi[k0 + t], ac[t]);
            #pragma unroll
            for (int t = 0; t < 4; t++) ac[t] = MF(Ahi, Blo[k0 + t], ac[t]);
            #pragma unroll
            for (int t = 0; t < 4; t++){
                float o = ow8[k0 + t];
                p0 += gelu_fast(ac[t][0]) * o;
                p1 += gelu_fast(ac[t][1]) * o;
                p2 += gelu_fast(ac[t][2]) * o;
                p3 += gelu_fast(ac[t][3]) * o;
            }
        }
        #pragma unroll
        for (int off = 1; off < 16; off <<= 1){
            p0 += __shfl_xor(p0, off, 16);
            p1 += __shfl_xor(p1, off, 16);
            p2 += __shfl_xor(p2, off, 16);
            p3 += __shfl_xor(p3, off, 16);
        }
        if (c == 0){
            long s = s0 + st * 16 + 4 * q;
            if (f32){
                float4 v = {p0 + obv, p1 + obv, p2 + obv, p3 + obv};
                *(float4*)((float*)out + (long)b * S_LEN + s) = v;
            } else {
                uint_t u0 = (uint_t)f2us(p0 + obv) | ((uint_t)f2us(p1 + obv) << 16);
                uint_t u1 = (uint_t)f2us(p2 + obv) | ((uint_t)f2us(p3 + obv) << 16);
                uint_t* gp = (uint_t*)((ushort_t*)out + (long)b * S_LEN + s);
                gp[0] = u0; gp[1] = u1;
            }
        }
    }
}

extern "C" void kernel_launch(void* const* d_in, const int* in_sizes, int n_in,
                              void* d_out, int out_size, void* d_ws, size_t ws_size,
                              hipStream_t stream) {
    const void* x   = d_in[0];
    const void* pw  = d_in[1];
    const void* pb  = d_in[2];
    const void* wre = d_in[3];
    const void* wim = d_in[4];
    const void* ow  = d_in[5];
    const void* ob  = d_in[6];

    char* ws = (char*)d_ws;
    ushort_t* Thi  = (ushort_t*)(ws);                  // 512 KB
    ushort_t* Tlo  = (ushort_t*)(ws + (512u << 10));   // 512 KB
    ushort_t* TThi = (ushort_t*)(ws + (1024u << 10));  // 512 KB
    float* C0    = (float*)(ws + (1536u << 10));       // 512 KB fp32 C ping
    float* C1    = (float*)(ws + (2048u << 10));       // 512 KB fp32 C pong
    float* Mfull = (float*)(ws + (2560u << 10));       // 512 KB fp32 M [b][j][k]
    float* Mpart = (float*)(ws + (3072u << 10));       // 16 MB fp32 [b][sx][j][k]

    const long wstride = (long)NH * NH * NM;

    k_prep<<<1024, 256, 0, stream>>>(x, pw, pb, Mfull, Thi, Tlo, TThi, C0);
    k_mixA<<<dim3(8, NBATCH), 256, 0, stream>>>(x, Mfull, wre, wim,
                                                0 * wstride, C0);
    k_fused3<<<dim3(32, NBATCH), 512, 0, stream>>>(Thi, Tlo, TThi, C0, C1, Mpart);
    k_reduce<<<dim3(16, NBATCH), 256, 0, stream>>>(Mpart, Mfull);
    k_mixA<<<dim3(8, NBATCH), 256, 0, stream>>>(x, Mfull, wre, wim,
                                                1 * wstride, C1);
    k_fused3<<<dim3(32, NBATCH), 512, 0, stream>>>(Thi, Tlo, TThi, C1, C0, Mpart);
    k_reduce<<<dim3(16, NBATCH), 256, 0, stream>>>(Mpart, Mfull);
    k_mixA<<<dim3(8, NBATCH), 256, 0, stream>>>(x, Mfull, wre, wim,
                                                2 * wstride, C0);
    k_fused3<<<dim3(32, NBATCH), 512, 0, stream>>>(Thi, Tlo, TThi, C0, C1, Mpart);
    k_reduce<<<dim3(16, NBATCH), 256, 0, stream>>>(Mpart, Mfull);
    k_mixA<<<dim3(8, NBATCH), 256, 0, stream>>>(x, Mfull, wre, wim,
                                                3 * wstride, C1);
    k_final<<<dim3(64, NBATCH), 256, 0, stream>>>(x, Thi, Tlo, C1, ow, ob, d_out);
}

// Round 9
// 245.000 us; speedup vs baseline: 1.1554x; 1.1085x over previous
//
#include <hip/hip_runtime.h>
#include <hip/hip_bf16.h>

#define S_LEN 8192
#define NH 128
#define NM 16
#define NB 32
#define NBATCH 32
#define GP2 136         // k_fused Glds s-pitch (128 + 8)

typedef __hip_bfloat16 bf16;
typedef unsigned short ushort_t;
typedef unsigned int uint_t;

typedef __bf16 bf16x8 __attribute__((ext_vector_type(8)));
typedef float floatx4 __attribute__((ext_vector_type(4)));

__device__ __forceinline__ float b2f(bf16 v){ return __bfloat162float(v); }
__device__ __forceinline__ float ldf(const void* p, long i, int f32){
    return f32 ? ((const float*)p)[i] : b2f(((const bf16*)p)[i]);
}
// A&S 7.1.26 erf, |eps|<=1.5e-7
__device__ __forceinline__ float gelu_fast(float x){
    float z = fabsf(x) * 0.70710678118654752440f;
    float t = __builtin_amdgcn_rcpf(__builtin_fmaf(0.3275911f, z, 1.0f));
    float p = t*(0.254829592f + t*(-0.284496736f + t*(1.421413741f +
              t*(-1.453152027f + t*1.061405429f))));
    float e = __expf(-z * z);
    float er = __builtin_fmaf(-p, e, 1.0f);
    float s = copysignf(er, x);
    return 0.5f * x * (1.0f + s);
}
__device__ __forceinline__ ushort_t f2us(float v){
    return __builtin_bit_cast(ushort_t, (__bf16)v);
}
__device__ __forceinline__ void split_bf(float v, ushort_t& hi, ushort_t& lo){
    __bf16 h = (__bf16)v;
    float r = v - (float)h;
    hi = __builtin_bit_cast(ushort_t, h);
    lo = __builtin_bit_cast(ushort_t, (__bf16)r);
}
__device__ __forceinline__ bf16x8 ld8(const ushort_t* p){
    return *(const bf16x8*)(const void*)p;
}
__device__ __forceinline__ floatx4 MF(bf16x8 a, bf16x8 b, floatx4 c){
    return __builtin_amdgcn_mfma_f32_16x16x32_bf16(a, b, c, 0, 0, 0);
}

// wave-0 dtype sniff (first 8 KB of x), broadcast via LDS. prep-only now.
__device__ __forceinline__ int detect_f32(const void* x, int tid){
    __shared__ int sflag;
    if (tid < 64){
        const ushort_t* p = (const ushort_t*)x;
        int cnt = 0;
        for (int i = tid; i < 4096; i += 64){
            int e = (p[i] >> 7) & 0xFF;
            if (e >= 0xA0) cnt++;
        }
        #pragma unroll
        for (int off = 32; off > 0; off >>= 1) cnt += __shfl_xor(cnt, off, 64);
        if (tid == 0) sflag = (cnt > 400) ? 1 : 0;
    }
    __syncthreads();
    return sflag;
}

// full-width C prologue: fp32 C[b][j][k] -> scaled bf16 hi/lo B-fragments.
__device__ __forceinline__ void c_prologue(const float* __restrict__ C,
                                           int b, int c, int q,
                                           bf16x8* Bhi, bf16x8* Blo){
    const float* Cb = C + (long)b * NB * NH;
    #pragma unroll
    for (int kt = 0; kt < 8; kt++){
        int k = kt * 16 + c;
        bf16x8 h8, l8;
        #pragma unroll
        for (int e = 0; e < 8; e++){
            int j = 8 * q + e;
            float sc = (j == 0) ? (1.0f / S_LEN)
                     : (j < NM) ? (2.0f / S_LEN)
                     : (j == NM) ? 0.f : (-2.0f / S_LEN);
            float v = Cb[j * NH + k] * sc;
            __bf16 hh = (__bf16)v;
            h8[e] = hh;
            l8[e] = (__bf16)(v - (float)hh);
        }
        Bhi[kt] = h8; Blo[kt] = l8;
    }
}

// ---- k_prep: blocks 0..511 modal DFT of x -> M (vectorized x loads);
//      512..1023 basis tables + zero C0; block 512 caches dtype flag.
__global__ __launch_bounds__(256) void k_prep(const void* __restrict__ x,
                                              const void* __restrict__ pw,
                                              const void* __restrict__ pb,
                                              float* __restrict__ M,
                                              ushort_t* __restrict__ Thi,
                                              ushort_t* __restrict__ Tlo,
                                              ushort_t* __restrict__ TThi,
                                              float* __restrict__ C0,
                                              uint_t* __restrict__ flag){
    int bid = blockIdx.x;
    int tid = threadIdx.x;
    int f32 = detect_f32(x, tid);
    if (bid < 512){
        int m = bid >> 5, b = bid & 31;
        float re = 0.f, im = 0.f;
        #pragma unroll
        for (int g = 0; g < 4; g++){
            int s0 = g * 2048 + tid * 8;
            float xv[8];
            if (f32){
                const float4* xp = (const float4*)((const float*)x
                                    + (long)b * S_LEN + s0);
                float4 v0 = xp[0], v1 = xp[1];
                xv[0]=v0.x; xv[1]=v0.y; xv[2]=v0.z; xv[3]=v0.w;
                xv[4]=v1.x; xv[5]=v1.y; xv[6]=v1.z; xv[7]=v1.w;
            } else {
                bf16x8 v = ld8((const ushort_t*)x + (long)b * S_LEN + s0);
                #pragma unroll
                for (int e = 0; e < 8; e++) xv[e] = (float)v[e];
            }
            if (m){
                #pragma unroll
                for (int e = 0; e < 8; e++){
                    int r = (m * (s0 + e)) & (S_LEN - 1);
                    float rev = (float)r * (1.0f / (float)S_LEN);
                    re += xv[e] * __builtin_amdgcn_cosf(rev);
                    im -= xv[e] * __builtin_amdgcn_sinf(rev);
                }
            } else {
                #pragma unroll
                for (int e = 0; e < 8; e++) re += xv[e];
            }
        }
        __shared__ float sred[8];
        #pragma unroll
        for (int off = 32; off > 0; off >>= 1){
            re += __shfl_xor(re, off, 64);
            im += __shfl_xor(im, off, 64);
        }
        int w = tid >> 6;
        if ((tid & 63) == 0){ sred[w] = re; sred[4 + w] = im; }
        __syncthreads();
        if (tid < NH){
            float Xre = sred[0] + sred[1] + sred[2] + sred[3];
            float Xim = sred[4] + sred[5] + sred[6] + sred[7];
            int h = tid;
            float pwv = ldf(pw, h, f32);
            float fc = pwv * Xre + (m == 0 ? (float)S_LEN * ldf(pb, h, f32) : 0.f);
            float fs = -pwv * Xim;
            float* Mb = M + (long)b * NB * NH;
            Mb[m * NH + h]        = fc;
            Mb[(NM + m) * NH + h] = fs;
        }
    } else {
        int bb = bid - 512;
        int s = bb * 16 + (tid >> 4);
        int m = tid & 15;
        float cv = 1.f, sv = 0.f;
        if (m){
            int r = (m * s) & (S_LEN - 1);
            float rev = (float)r * (1.0f / (float)S_LEN);
            sv = __builtin_amdgcn_sinf(rev);
            cv = __builtin_amdgcn_cosf(rev);
        }
        ushort_t chi, clo, shi, slo;
        split_bf(cv, chi, clo);
        split_bf(sv, shi, slo);
        Thi[s * NB + m] = chi;       Tlo[s * NB + m] = clo;
        Thi[s * NB + NM + m] = shi;  Tlo[s * NB + NM + m] = slo;
        TThi[m * S_LEN + s] = chi;
        TThi[(NM + m) * S_LEN + s] = shi;
        C0[bb * 256 + tid] = 0.f;    // zero layer-0 C buffer
        if (bb == 0 && tid == 0) flag[0] = (uint_t)f32;
    }
}

// ---- mixA: mode-split grid (8 hc, 2 mg, 32 b) = 512 blocks (2/CU).
//      Stage M[b] 16-h chunk -> 8-mode partial C -> atomic into C[b][j][k].
__global__ __launch_bounds__(256) void k_mixA(const uint_t* __restrict__ flag,
                                              const float* __restrict__ M,
                                              const void* __restrict__ wre,
                                              const void* __restrict__ wim,
                                              long woff,
                                              float* __restrict__ C){
    int tid = threadIdx.x;
    int f32 = (int)flag[0];
    int hc = blockIdx.x, mg = blockIdx.y, b = blockIdx.z;
    int k = tid & 127, msub = tid >> 7;
    int m0 = mg * 8 + msub * 4;     // 4 modes per thread
    int h0 = hc * 16;
    __shared__ float Ms[NB * 16];
    for (int i = tid; i < NB * 16; i += 256){
        int j = i >> 4, hh = i & 15;
        Ms[j * 16 + hh] = M[(long)b * NB * NH + j * NH + h0 + hh];
    }
    __syncthreads();
    float Cr[4] = {0,0,0,0}, Ci[4] = {0,0,0,0};
    #pragma unroll 8
    for (int hh = 0; hh < 16; hh++){
        long base = woff + ((long)(h0 + hh) * NH + k) * NM + m0;
        float wr[4], wi[4];
        if (f32){
            float4 a  = *(const float4*)((const float*)wre + base);
            float4 cc = *(const float4*)((const float*)wim + base);
            wr[0]=a.x;  wr[1]=a.y;  wr[2]=a.z;  wr[3]=a.w;
            wi[0]=cc.x; wi[1]=cc.y; wi[2]=cc.z; wi[3]=cc.w;
        } else {
            ushort4 a  = *(const ushort4*)((const ushort_t*)wre + base);
            ushort4 cc = *(const ushort4*)((const ushort_t*)wim + base);
            wr[0]=b2f(__builtin_bit_cast(bf16, a.x));
            wr[1]=b2f(__builtin_bit_cast(bf16, a.y));
            wr[2]=b2f(__builtin_bit_cast(bf16, a.z));
            wr[3]=b2f(__builtin_bit_cast(bf16, a.w));
            wi[0]=b2f(__builtin_bit_cast(bf16, cc.x));
            wi[1]=b2f(__builtin_bit_cast(bf16, cc.y));
            wi[2]=b2f(__builtin_bit_cast(bf16, cc.z));
            wi[3]=b2f(__builtin_bit_cast(bf16, cc.w));
        }
        #pragma unroll
        for (int e = 0; e < 4; e++){
            float fc = Ms[(m0 + e) * 16 + hh];
            float fs = Ms[(NM + m0 + e) * 16 + hh];
            Cr[e] += fc * wr[e] + fs * wi[e];
            Ci[e] += fc * wi[e] - fs * wr[e];
        }
    }
    float* Cb = C + (long)b * NB * NH;
    #pragma unroll
    for (int e = 0; e < 4; e++){
        atomicAdd(&Cb[(m0 + e) * NH + k],      Cr[e]);
        atomicAdd(&Cb[(NM + m0 + e) * NH + k], Ci[e]);
    }
}

// ---- k_reduce: sum the 32 per-block M partials -> Mfull. Fully coalesced.
__global__ __launch_bounds__(256) void k_reduce(const float* __restrict__ Mpart,
                                                float* __restrict__ Mfull){
    int r = blockIdx.x, b = blockIdx.y;
    int idx = r * 256 + threadIdx.x;
    const float* mp = Mpart + (long)b * 32 * (NB * NH) + idx;
    float acc = 0.f;
    #pragma unroll
    for (int sx = 0; sx < 32; sx++) acc += mp[(long)sx * (NB * NH)];
    Mfull[(long)b * (NB * NH) + idx] = acc;
}

// ---- fused layer (round-0 r14 body): C prologue -> MFMA synth -> gelu ->
//      MFMA DFT -> plain-store per-block M partial.
__global__ __launch_bounds__(256, 4) void k_fused(const ushort_t* __restrict__ Thi,
                                                  const ushort_t* __restrict__ Tlo,
                                                  const ushort_t* __restrict__ TThi,
                                                  const float* __restrict__ C,
                                                  float* __restrict__ Cnext,
                                                  float* __restrict__ Mpart){
    int b = blockIdx.y;
    int sx = blockIdx.x;
    int s0 = sx * 256;
    int tid = threadIdx.x;
    int w = tid >> 6;
    int lane = tid & 63;
    int c = lane & 15, q = lane >> 4;
    __shared__ __align__(16) ushort_t Glds[NH * GP2];

    bf16x8 Bhi[8], Blo[8];
    c_prologue(C, b, c, q, Bhi, Blo);
    if (tid < 32){
        *(float4*)(Cnext + (long)b * NB * NH + sx * 128 + tid * 4)
            = (float4){0.f, 0.f, 0.f, 0.f};
    }
    floatx4 a00 = {0,0,0,0}, a01 = {0,0,0,0}, a10 = {0,0,0,0}, a11 = {0,0,0,0};
    int kt0 = 2 * w;
    for (int p = 0; p < 2; p++){
        int sp = s0 + p * 128;
        #pragma unroll
        for (int sti = 0; sti < 2; sti++){
            int st = w * 2 + sti;
            long ar = (long)(sp + st * 16 + c) * NB + 8 * q;
            bf16x8 Ahi = ld8(Thi + ar);
            bf16x8 Alo = ld8(Tlo + ar);
            #pragma unroll
            for (int kt = 0; kt < 8; kt++){
                floatx4 acc = {0.f, 0.f, 0.f, 0.f};
                acc = MF(Ahi, Bhi[kt], acc);
                acc = MF(Alo, Bhi[kt], acc);
                acc = MF(Ahi, Blo[kt], acc);
                uint_t u0 = (uint_t)f2us(gelu_fast(acc[0])) |
                            ((uint_t)f2us(gelu_fast(acc[1])) << 16);
                uint_t u1 = (uint_t)f2us(gelu_fast(acc[2])) |
                            ((uint_t)f2us(gelu_fast(acc[3])) << 16);
                uint_t* gp = (uint_t*)&Glds[(kt * 16 + c) * GP2 + st * 16 + 4 * q];
                gp[0] = u0; gp[1] = u1;
            }
        }
        __syncthreads();
        #pragma unroll
        for (int kk = 0; kk < 4; kk++){
            long sa = (long)sp + kk * 32 + 8 * q;
            bf16x8 A0h = ld8(TThi + (long)c * S_LEN + sa);
            bf16x8 A1h = ld8(TThi + (long)(16 + c) * S_LEN + sa);
            bf16x8 G0 = ld8(&Glds[(kt0 * 16 + c) * GP2 + kk * 32 + 8 * q]);
            bf16x8 G1 = ld8(&Glds[((kt0 + 1) * 16 + c) * GP2 + kk * 32 + 8 * q]);
            a00 = MF(A0h, G0, a00);
            a01 = MF(A0h, G1, a01);
            a10 = MF(A1h, G0, a10);
            a11 = MF(A1h, G1, a11);
        }
        __syncthreads();
    }
    // block-private partial slice: plain coalesced stores, no atomics
    float* Mb = Mpart + ((long)b * 32 + sx) * (NB * NH);
    #pragma unroll
    for (int r = 0; r < 4; r++){
        Mb[(4 * q + r) * NH + kt0 * 16 + c]            = a00[r];
        Mb[(4 * q + r) * NH + (kt0 + 1) * 16 + c]      = a01[r];
        Mb[(16 + 4 * q + r) * NH + kt0 * 16 + c]       = a10[r];
        Mb[(16 + 4 * q + r) * NH + (kt0 + 1) * 16 + c] = a11[r];
    }
}

// ---- final: C prologue -> MFMA synth (ILP-grouped; big reg budget) -> out
__global__ __launch_bounds__(256) void k_final(const uint_t* __restrict__ flag,
                                               const ushort_t* __restrict__ Thi,
                                               const ushort_t* __restrict__ Tlo,
                                               const float* __restrict__ C,
                                               const void* __restrict__ ow,
                                               const void* __restrict__ ob,
                                               void* __restrict__ out){
    int tid = threadIdx.x;
    int f32 = (int)flag[0];
    int b = blockIdx.y;
    int s0 = blockIdx.x * 128;
    int w = tid >> 6;
    int lane = tid & 63;
    int c = lane & 15, q = lane >> 4;

    bf16x8 Bhi[8], Blo[8];
    c_prologue(C, b, c, q, Bhi, Blo);
    float ow8[8];
    #pragma unroll
    for (int kt = 0; kt < 8; kt++) ow8[kt] = ldf(ow, kt * 16 + c, f32);
    float obv = ldf(ob, 0, f32);
    #pragma unroll
    for (int sti = 0; sti < 2; sti++){
        int st = w * 2 + sti;
        long ar = (long)(s0 + st * 16 + c) * NB + 8 * q;
        bf16x8 Ahi = ld8(Thi + ar);
        bf16x8 Alo = ld8(Tlo + ar);
        float p0 = 0.f, p1 = 0.f, p2 = 0.f, p3 = 0.f;
        #pragma unroll
        for (int g = 0; g < 2; g++){
            int k0 = g * 4;
            floatx4 ac[4];
            #pragma unroll
            for (int t = 0; t < 4; t++) ac[t] = (floatx4){0.f, 0.f, 0.f, 0.f};
            #pragma unroll
            for (int t = 0; t < 4; t++) ac[t] = MF(Ahi, Bhi[k0 + t], ac[t]);
            #pragma unroll
            for (int t = 0; t < 4; t++) ac[t] = MF(Alo, Bhi[k0 + t], ac[t]);
            #pragma unroll
            for (int t = 0; t < 4; t++) ac[t] = MF(Ahi, Blo[k0 + t], ac[t]);
            #pragma unroll
            for (int t = 0; t < 4; t++){
                float o = ow8[k0 + t];
                p0 += gelu_fast(ac[t][0]) * o;
                p1 += gelu_fast(ac[t][1]) * o;
                p2 += gelu_fast(ac[t][2]) * o;
                p3 += gelu_fast(ac[t][3]) * o;
            }
        }
        #pragma unroll
        for (int off = 1; off < 16; off <<= 1){
            p0 += __shfl_xor(p0, off, 16);
            p1 += __shfl_xor(p1, off, 16);
            p2 += __shfl_xor(p2, off, 16);
            p3 += __shfl_xor(p3, off, 16);
        }
        if (c == 0){
            long s = s0 + st * 16 + 4 * q;
            if (f32){
                float4 v = {p0 + obv, p1 + obv, p2 + obv, p3 + obv};
                *(float4*)((float*)out + (long)b * S_LEN + s) = v;
            } else {
                uint_t u0 = (uint_t)f2us(p0 + obv) | ((uint_t)f2us(p1 + obv) << 16);
                uint_t u1 = (uint_t)f2us(p2 + obv) | ((uint_t)f2us(p3 + obv) << 16);
                uint_t* gp = (uint_t*)((ushort_t*)out + (long)b * S_LEN + s);
                gp[0] = u0; gp[1] = u1;
            }
        }
    }
}

extern "C" void kernel_launch(void* const* d_in, const int* in_sizes, int n_in,
                              void* d_out, int out_size, void* d_ws, size_t ws_size,
                              hipStream_t stream) {
    const void* x   = d_in[0];
    const void* pw  = d_in[1];
    const void* pb  = d_in[2];
    const void* wre = d_in[3];
    const void* wim = d_in[4];
    const void* ow  = d_in[5];
    const void* ob  = d_in[6];

    char* ws = (char*)d_ws;
    ushort_t* Thi  = (ushort_t*)(ws);                  // 512 KB
    ushort_t* Tlo  = (ushort_t*)(ws + (512u << 10));   // 512 KB
    ushort_t* TThi = (ushort_t*)(ws + (1024u << 10));  // 512 KB
    float* C0    = (float*)(ws + (1536u << 10));       // 512 KB fp32 C ping
    float* C1    = (float*)(ws + (2048u << 10));       // 512 KB fp32 C pong
    float* Mfull = (float*)(ws + (2560u << 10));       // 512 KB fp32 M [b][j][k]
    uint_t* flag = (uint_t*)(ws + (3072u << 10));      // dtype flag (4 B)
    float* Mpart = (float*)(ws + (3136u << 10));       // 16 MB fp32 [b][sx][j][k]

    const long wstride = (long)NH * NH * NM;

    k_prep<<<1024, 256, 0, stream>>>(x, pw, pb, Mfull, Thi, Tlo, TThi, C0, flag);
    k_mixA<<<dim3(8, 2, NBATCH), 256, 0, stream>>>(flag, Mfull, wre, wim,
                                                   0 * wstride, C0);
    k_fused<<<dim3(32, NBATCH), 256, 0, stream>>>(Thi, Tlo, TThi, C0, C1, Mpart);
    k_reduce<<<dim3(16, NBATCH), 256, 0, stream>>>(Mpart, Mfull);
    k_mixA<<<dim3(8, 2, NBATCH), 256, 0, stream>>>(flag, Mfull, wre, wim,
                                                   1 * wstride, C1);
    k_fused<<<dim3(32, NBATCH), 256, 0, stream>>>(Thi, Tlo, TThi, C1, C0, Mpart);
    k_reduce<<<dim3(16, NBATCH), 256, 0, stream>>>(Mpart, Mfull);
    k_mixA<<<dim3(8, 2, NBATCH), 256, 0, stream>>>(flag, Mfull, wre, wim,
                                                   2 * wstride, C0);
    k_fused<<<dim3(32, NBATCH), 256, 0, stream>>>(Thi, Tlo, TThi, C0, C1, Mpart);
    k_reduce<<<dim3(16, NBATCH), 256, 0, stream>>>(Mpart, Mfull);
    k_mixA<<<dim3(8, 2, NBATCH), 256, 0, stream>>>(flag, Mfull, wre, wim,
                                                   3 * wstride, C1);
    k_final<<<dim3(64, NBATCH), 256, 0, stream>>>(flag, Thi, Tlo, C1,
                                                  ow, ob, d_out);
}